// Round 10
// baseline (178.874 us; speedup 1.0000x reference)
//
#include <hip/hip_runtime.h>
#include <stdint.h>
#include <stddef.h>

// Problem: B=4, C=256, CR=32, H=W=64, N=4096
#define Bn 4
#define Cn 256
#define CRn 32
#define Nn 4096

typedef __attribute__((ext_vector_type(8))) short short8v;  // 8 bf16 (4 VGPR)
typedef __attribute__((ext_vector_type(4))) float f32x4;

__device__ __forceinline__ unsigned short f2bf(float f) {
  unsigned int u = __float_as_uint(f);
  u += 0x7FFFu + ((u >> 16) & 1u);   // RNE
  return (unsigned short)(u >> 16);
}

// ---------------- kernel 0: cast W (Wq|Wk|Wv rows) -> Wb [320][256] bf16 ----------------
__global__ void __launch_bounds__(256) k_wcast(const float* __restrict__ Wq,
                                               const float* __restrict__ Wk,
                                               const float* __restrict__ Wv,
                                               unsigned short* __restrict__ Wb) {
  int idx = (blockIdx.x * 256 + threadIdx.x) * 4;   // 80 blocks -> 81920 elems
  int row = idx >> 8, cc = idx & 255;
  const float* src = (row < 32) ? &Wq[row * 256 + cc]
                   : (row < 64) ? &Wk[(row - 32) * 256 + cc]
                                : &Wv[(row - 64) * 256 + cc];
  float4 f = *reinterpret_cast<const float4*>(src);
  ushort4 o;
  o.x = f2bf(f.x); o.y = f2bf(f.y); o.z = f2bf(f.z); o.w = f2bf(f.w);
  *reinterpret_cast<ushort4*>(&Wb[idx]) = o;
}

// ---------------- kernel 1: fused transpose + projections (all 320 rows/block) ----------------
// grid (nt 128, b 4) = 512 blocks, 512 thr. n-tile = 32 cols. x read ONCE.
// 8 waves = nw(2, n-halves of 16) x rh(4, row-quarters of 80).
__global__ void __launch_bounds__(512) k_proj(const unsigned short* __restrict__ Wb,
                                              const float* __restrict__ x,
                                              unsigned short* __restrict__ Qt,
                                              unsigned short* __restrict__ Kt,
                                              unsigned short* __restrict__ V) {
  __shared__ __align__(16) unsigned char smem[58112];
  unsigned short* xs   = (unsigned short*)smem;              // [32 n][268 c] bf16 (17152 B)
  unsigned short* wbuf = (unsigned short*)(smem + 17152);    // 2 x [320][32] bf16 (2x20480 B)
  float*          xf   = (float*)(smem + 17152);             // [64 c][33 n] f32 (staging alias)
  unsigned short* vb   = (unsigned short*)smem;              // [256][40] bf16 (epilogue alias)

  const int t  = threadIdx.x;
  const int nt = blockIdx.x, b = blockIdx.y;

  // ---- stage x^T tile [32 n][256 c]: 4 rounds of 64 channels ----
  const int cs = t >> 3, nq8 = t & 7;       // cs 0..63, nq8*4 = n-quad
  for (int ct = 0; ct < 4; ++ct) {
    if (ct) __syncthreads();                // xf reuse
    float4 f = *reinterpret_cast<const float4*>(
        &x[(((size_t)((b << 8) + (ct << 6) + cs)) << 12) + (nt << 5) + (nq8 << 2)]);
    xf[cs * 33 + (nq8 << 2) + 0] = f.x;
    xf[cs * 33 + (nq8 << 2) + 1] = f.y;
    xf[cs * 33 + (nq8 << 2) + 2] = f.z;
    xf[cs * 33 + (nq8 << 2) + 3] = f.w;
    __syncthreads();
    int nl = t >> 4;            // 0..31
    int cq = (t & 15) << 2;     // 0..60
    ushort4 o;
    o.x = f2bf(xf[(cq + 0) * 33 + nl]);
    o.y = f2bf(xf[(cq + 1) * 33 + nl]);
    o.z = f2bf(xf[(cq + 2) * 33 + nl]);
    o.w = f2bf(xf[(cq + 3) * 33 + nl]);
    *reinterpret_cast<ushort4*>(&xs[nl * 268 + (ct << 6) + cq]) = o;
  }
  __syncthreads();   // xf dead from here; wbuf region free

  // Wb slice staging: 1280 16B-units: row = idx>>2 (0..319), seg = idx&3.
  // LDS[row][seg] = Wb[row][ks*32 + (seg ^ fsw(row))*8], fsw = (row^(row>>2))&3
  auto STAGEWB = [&](int ks, int buf) {
#pragma unroll
    for (int r = 0; r < 3; ++r) {
      int idx = (r << 9) + t;
      if (idx < 1280) {
        int row = idx >> 2, seg = idx & 3;
        int sseg = seg ^ ((row ^ (row >> 2)) & 3);
        const unsigned short* g = Wb + (((size_t)row) << 8) + (ks << 5) + (sseg << 3);
        __builtin_amdgcn_global_load_lds(
            (const __attribute__((address_space(1))) void*)g,
            (__attribute__((address_space(3))) void*)(wbuf + buf * 10240 + idx * 8),
            16, 0, 0);
      }
    }
  };

  STAGEWB(0, 0);
  __syncthreads();

  const int lane = t & 63, w = t >> 6, col = lane & 15, hi = lane >> 4;
  const int nw = w & 1, rh = w >> 1;       // n-half, row-quarter (80 rows)
  f32x4 zero4 = {0.f, 0.f, 0.f, 0.f};
  f32x4 acc[5];
#pragma unroll
  for (int rc = 0; rc < 5; ++rc) acc[rc] = zero4;

#pragma unroll 1
  for (int ks = 0; ks < 8; ++ks) {
    const unsigned short* wB = wbuf + (ks & 1) * 10240;
    if (ks < 7) STAGEWB(ks + 1, (ks & 1) ^ 1);
    short8v af = *reinterpret_cast<const short8v*>(
        &xs[((nw << 4) + col) * 268 + (ks << 5) + (hi << 3)]);
#pragma unroll
    for (int rc = 0; rc < 5; ++rc) {
      int row = rh * 80 + (rc << 4) + col;
      int sw = hi ^ ((row ^ (row >> 2)) & 3);
      short8v bf = *reinterpret_cast<const short8v*>(wB + row * 32 + (sw << 3));
      acc[rc] = __builtin_amdgcn_mfma_f32_16x16x32_bf16(af, bf, acc[rc], 0, 0, 0);
    }
    __syncthreads();   // drains vmcnt (next-slice gload_lds) + lgkm
  }

  // ---- Q/K outputs (rh==0: rows 0..79 -> Q 0..31, K 32..63, V 64..79) ----
  if (rh == 0) {
#pragma unroll
    for (int rc = 0; rc < 2; ++rc)
#pragma unroll
      for (int r = 0; r < 4; ++r) {
        int n = (nt << 5) + (nw << 4) + (hi << 2) + r;
        Qt[(((size_t)((b << 12) + n)) << 5) + (rc << 4) + col] = f2bf(acc[rc][r]);
      }
#pragma unroll
    for (int rc = 2; rc < 4; ++rc)
#pragma unroll
      for (int r = 0; r < 4; ++r) {
        int n = (nt << 5) + (nw << 4) + (hi << 2) + r;
        Kt[(((size_t)((b << 12) + n)) << 5) + ((rc - 2) << 4) + col] = f2bf(acc[rc][r]);
      }
  }

  // ---- V channels -> vb[ch][40] (xs/wbuf-buf0 dead; alias) ----
  {
    const int nb = (nw << 4) + (hi << 2);
    const int rcStart = (rh == 0) ? 4 : 0;
#pragma unroll
    for (int rc = 0; rc < 5; ++rc) {
      if (rc < rcStart) continue;
      int ch = rh * 80 + (rc << 4) + col - 64;
#pragma unroll
      for (int r = 0; r < 4; ++r)
        vb[ch * 40 + nb + r] = f2bf(acc[rc][r]);
    }
  }
  __syncthreads();

  // ---- coalesced V store: 1024 x 16B units (4 per channel row) ----
#pragma unroll
  for (int p = 0; p < 2; ++p) {
    int idx = (p << 9) + t;
    int c = idx >> 2, off = idx & 3;
    int offp = off ^ (c & 3);   // bank spread; same 64B global segment set
    int4 dv = *reinterpret_cast<const int4*>(&vb[c * 40 + (offp << 3)]);
    *reinterpret_cast<int4*>(
        &V[(((size_t)((b << 8) + c)) << 12) + (nt << 5) + (offp << 3)]) = dv;
  }
}

// ---------------- kernel 2: flash attention ----------------
// grid 512 = (b 4) x (ch 2) x (qt 64). 8 waves: g = KV-half, wg = col-group/ch-slice.
// K/V direct from L2 into regs, prefetch across single lgkm-only barrier per phase.
// VALU diet: cvt_pk P-pack + T13 skip-rescale (both bit-identical numerics).
__global__ void __launch_bounds__(512, 2) k_attn(const unsigned short* __restrict__ Qt,
                                                 const unsigned short* __restrict__ Kt,
                                                 const unsigned short* __restrict__ Vv,
                                                 const float* __restrict__ x,
                                                 float* __restrict__ out) {
  __shared__ unsigned short Qs[64][40];
  __shared__ __align__(16) unsigned short Pt[2][2][64 * 64];  // [g][parity], 16B-unit XOR swz
  __shared__ float Sc[2][2][64];
  __shared__ float Mm[2][64], Ll[2][64];
  __shared__ float Ob[4][16][64];

  const int t = threadIdx.x, bx = blockIdx.x;
  const int xcd = bx & 7;                 // XCD-locality: fixed (b,ch) per XCD
  const int b = xcd >> 1, ch = xcd & 1;
  const int qt = bx >> 3;                 // 0..63
  const int lane = t & 63, w = t >> 6, col = lane & 15, hi = lane >> 4;
  const int g = w >> 2, wg = w & 3;
  const int cBase = (ch << 7) + (wg << 5);

  if (t < 256) {  // stage Q tile [64][32]
    const int mr = t >> 2, u = t & 3;
    int4 d = *reinterpret_cast<const int4*>(
        Qt + (((size_t)((b << 12) + (qt << 6) + mr)) << 5) + (u << 3));
    *reinterpret_cast<int4*>(&Qs[mr][u << 3]) = d;
  }

  const unsigned short* KtB = Kt + (((size_t)(b << 12)) << 5);
  const unsigned short* VvB = Vv + (((size_t)((b << 8) + cBase)) << 12);

  const int kt0 = g << 5;
  int m0 = kt0 << 6;
  short8v kf[4], vf[4];
#pragma unroll
  for (int mb = 0; mb < 4; ++mb)
    kf[mb] = *reinterpret_cast<const short8v*>(
        KtB + (((size_t)(m0 + (mb << 4) + col)) << 5) + (hi << 3));
#pragma unroll
  for (int ks = 0; ks < 2; ++ks)
#pragma unroll
    for (int cb = 0; cb < 2; ++cb)
      vf[(ks << 1) + cb] = *reinterpret_cast<const short8v*>(
          VvB + (((size_t)((cb << 4) + col)) << 12) + m0 + (ks << 5) + (hi << 3));
  __syncthreads();
  const short8v qf = *reinterpret_cast<const short8v*>(&Qs[(wg << 4) + col][hi << 3]);

  f32x4 zero4 = {0.f, 0.f, 0.f, 0.f};
  f32x4 o_acc[2][4];
#pragma unroll
  for (int cb = 0; cb < 2; ++cb)
#pragma unroll
    for (int nc = 0; nc < 4; ++nc) o_acc[cb][nc] = zero4;
  float m_run = -3e38f, l_run = 0.f;

#pragma unroll 1
  for (int i = 0; i < 32; ++i) {
    const int p = i & 1;
    const int iNext = (i < 31) ? (i + 1) : 31;
    const int mN = (kt0 + iNext) << 6;

    // ---- S^T slice: rows m (4 chunks), cols n = wg*16..+15 ----
    f32x4 s_acc[4];
#pragma unroll
    for (int mb = 0; mb < 4; ++mb)
      s_acc[mb] = __builtin_amdgcn_mfma_f32_16x16x32_bf16(kf[mb], qf, zero4, 0, 0, 0);
    // K prefetch next tile (WAR on kf orders after the MFMAs)
#pragma unroll
    for (int mb = 0; mb < 4; ++mb)
      kf[mb] = *reinterpret_cast<const short8v*>(
          KtB + (((size_t)(mN + (mb << 4) + col)) << 5) + (hi << 3));

    // ---- wave-local online softmax (column n = qt*64 + wg*16 + col) ----
    float tm = -3e38f;
#pragma unroll
    for (int mb = 0; mb < 4; ++mb)
#pragma unroll
      for (int r = 0; r < 4; ++r) tm = fmaxf(tm, s_acc[mb][r]);
    tm = fmaxf(tm, __shfl_xor(tm, 16));
    tm = fmaxf(tm, __shfl_xor(tm, 32));
    // T13: skip max-update when no column in this wave grew (bit-identical: sc==1 exactly)
    float mn, sc;
    if (__any(tm > m_run)) {
      mn = fmaxf(m_run, tm);
      sc = __expf(m_run - mn);
      m_run = mn;
    } else {
      mn = m_run;
      sc = 1.f;
    }
    float ps = 0.f;
#pragma unroll
    for (int mb = 0; mb < 4; ++mb)
#pragma unroll
      for (int r = 0; r < 4; ++r) {
        float pv = __expf(s_acc[mb][r] - mn);
        s_acc[mb][r] = pv;
        ps += pv;
      }
    ps += __shfl_xor(ps, 16);
    ps += __shfl_xor(ps, 32);
    l_run = l_run * sc + ps;
    if (hi == 0) Sc[g][p][(wg << 4) + col] = sc;
    // P^T bf16 -> Pt[g][p] via v_cvt_pk_bf16_f32 (RNE, same bits as f2bf for our range)
#pragma unroll
    for (int mb = 0; mb < 4; ++mb) {
      uint2 pk2;
      asm("v_cvt_pk_bf16_f32 %0, %1, %2"
          : "=v"(pk2.x) : "v"(s_acc[mb][0]), "v"(s_acc[mb][1]));
      asm("v_cvt_pk_bf16_f32 %0, %1, %2"
          : "=v"(pk2.y) : "v"(s_acc[mb][2]), "v"(s_acc[mb][3]));
      int uu = (mb << 1) + (hi >> 1);
      int up = uu ^ (col & 7);
      *reinterpret_cast<uint2*>(
          &Pt[g][p][(((wg << 4) + col) << 6) + (up << 3) + ((hi & 1) << 2)]) = pk2;
    }

    // ---- single barrier: drain LDS writes only; V/K loads stay in flight ----
    asm volatile("s_waitcnt lgkmcnt(0)" ::: "memory");
    __builtin_amdgcn_s_barrier();

    // ---- rescale (skipped when all scl==1) + PV ----
    float scl[4];
#pragma unroll
    for (int nc = 0; nc < 4; ++nc) scl[nc] = Sc[g][p][(nc << 4) + col];
    if (__any((scl[0] != 1.f) | (scl[1] != 1.f) | (scl[2] != 1.f) | (scl[3] != 1.f))) {
#pragma unroll
      for (int cb = 0; cb < 2; ++cb)
#pragma unroll
        for (int nc = 0; nc < 4; ++nc) o_acc[cb][nc] *= scl[nc];
    }
#pragma unroll
    for (int ks = 0; ks < 2; ++ks) {
      short8v pb[4];
      int up2 = ((ks << 2) + hi) ^ (col & 7);
#pragma unroll
      for (int nc = 0; nc < 4; ++nc)
        pb[nc] = *reinterpret_cast<const short8v*>(
            &Pt[g][p][(((nc << 4) + col) << 6) + (up2 << 3)]);
#pragma unroll
      for (int cb = 0; cb < 2; ++cb)
#pragma unroll
        for (int nc = 0; nc < 4; ++nc)
          o_acc[cb][nc] = __builtin_amdgcn_mfma_f32_16x16x32_bf16(
              vf[(ks << 1) + cb], pb[nc], o_acc[cb][nc], 0, 0, 0);
    }
    // V prefetch next tile (WAR on vf orders after the MFMAs; in flight across barrier)
#pragma unroll
    for (int ks = 0; ks < 2; ++ks)
#pragma unroll
      for (int cb = 0; cb < 2; ++cb)
        vf[(ks << 1) + cb] = *reinterpret_cast<const short8v*>(
            VvB + (((size_t)((cb << 4) + col)) << 12) + mN + (ks << 5) + (hi << 3));
  }

  // ---- merge the two KV-groups + epilogue ----
  if (hi == 0) { Mm[g][(wg << 4) + col] = m_run; Ll[g][(wg << 4) + col] = l_run; }
  __syncthreads();
  float fa[4], fb[4], linv[4];
#pragma unroll
  for (int nc = 0; nc < 4; ++nc) {
    float ma = Mm[0][(nc << 4) + col], mb2 = Mm[1][(nc << 4) + col];
    float mm = fmaxf(ma, mb2);
    float ea = __expf(ma - mm), eb = __expf(mb2 - mm);
    linv[nc] = 1.f / (Ll[0][(nc << 4) + col] * ea + Ll[1][(nc << 4) + col] * eb);
    fa[nc] = ea; fb[nc] = eb;
  }
#pragma unroll
  for (int cb = 0; cb < 2; ++cb) {
    if (g == 1) {
#pragma unroll
      for (int nc = 0; nc < 4; ++nc)
#pragma unroll
        for (int r = 0; r < 4; ++r)
          Ob[wg][(nc << 2) + r][lane] = o_acc[cb][nc][r];
    }
    __syncthreads();
    if (g == 0) {
#pragma unroll
      for (int nc = 0; nc < 4; ++nc)
#pragma unroll
        for (int r = 0; r < 4; ++r) {
          float o = o_acc[cb][nc][r] * fa[nc] + Ob[wg][(nc << 2) + r][lane] * fb[nc];
          int cg = cBase + (cb << 4) + (hi << 2) + r;
          int ng = (qt << 6) + (nc << 4) + col;
          size_t off = (((size_t)((b << 8) + cg)) << 12) + ng;
          out[off] = o * linv[nc] + x[off];
        }
    }
    __syncthreads();
  }
}

// ---------------- launcher ----------------
extern "C" void kernel_launch(void* const* d_in, const int* in_sizes, int n_in,
                              void* d_out, int out_size, void* d_ws, size_t ws_size,
                              hipStream_t stream) {
  (void)in_sizes; (void)n_in; (void)out_size; (void)ws_size;
  const float* x  = (const float*)d_in[0];
  const float* Wq = (const float*)d_in[1];
  const float* Wk = (const float*)d_in[2];
  const float* Wv = (const float*)d_in[3];
  float* out = (float*)d_out;

  unsigned short* Qt = (unsigned short*)d_ws;                      // [B][N][32]  1.05 MB
  unsigned short* Kt = Qt + (size_t)Bn * Nn * CRn;                 // [B][N][32]  1.05 MB
  unsigned short* Vv = Kt + (size_t)Bn * Nn * CRn;                 // [B][C][N]   8.39 MB
  unsigned short* Wb = Vv + (size_t)Bn * Cn * Nn;                  // [320][256]  164 KB

  hipLaunchKernelGGL(k_wcast, dim3(80),        dim3(256), 0, stream, Wq, Wk, Wv, Wb);
  hipLaunchKernelGGL(k_proj,  dim3(128, 4),    dim3(512), 0, stream, Wb, x, Qt, Kt, Vv);
  hipLaunchKernelGGL(k_attn,  dim3(512),       dim3(512), 0, stream, Qt, Kt, Vv, x, out);
}

// Round 11
// 176.242 us; speedup vs baseline: 1.0149x; 1.0149x over previous
//
#include <hip/hip_runtime.h>
#include <stdint.h>
#include <stddef.h>

// Problem: B=4, C=256, CR=32, H=W=64, N=4096
#define Bn 4
#define Cn 256
#define CRn 32
#define Nn 4096

typedef __attribute__((ext_vector_type(8))) short short8v;  // 8 bf16 (4 VGPR)
typedef __attribute__((ext_vector_type(4))) float f32x4;

__device__ __forceinline__ unsigned short f2bf(float f) {
  unsigned int u = __float_as_uint(f);
  u += 0x7FFFu + ((u >> 16) & 1u);   // RNE
  return (unsigned short)(u >> 16);
}

// ---------------- kernel 0: cast W (Wq|Wk|Wv rows) -> Wb [320][256] bf16 ----------------
__global__ void __launch_bounds__(256) k_wcast(const float* __restrict__ Wq,
                                               const float* __restrict__ Wk,
                                               const float* __restrict__ Wv,
                                               unsigned short* __restrict__ Wb) {
  int idx = (blockIdx.x * 256 + threadIdx.x) * 4;   // 80 blocks -> 81920 elems
  int row = idx >> 8, cc = idx & 255;
  const float* src = (row < 32) ? &Wq[row * 256 + cc]
                   : (row < 64) ? &Wk[(row - 32) * 256 + cc]
                                : &Wv[(row - 64) * 256 + cc];
  float4 f = *reinterpret_cast<const float4*>(src);
  ushort4 o;
  o.x = f2bf(f.x); o.y = f2bf(f.y); o.z = f2bf(f.z); o.w = f2bf(f.w);
  *reinterpret_cast<ushort4*>(&Wb[idx]) = o;
}

// ---------------- kernel 1: fused transpose + projections (all 320 rows/block) ----------------
// grid (nt 128, b 4) = 512 blocks, 512 thr. n-tile = 32 cols. x read ONCE.
// 8 waves = nw(2, n-halves of 16) x rh(4, row-quarters of 80).
__global__ void __launch_bounds__(512) k_proj(const unsigned short* __restrict__ Wb,
                                              const float* __restrict__ x,
                                              unsigned short* __restrict__ Qt,
                                              unsigned short* __restrict__ Kt,
                                              unsigned short* __restrict__ V) {
  __shared__ __align__(16) unsigned char smem[58112];
  unsigned short* xs   = (unsigned short*)smem;              // [32 n][268 c] bf16 (17152 B)
  unsigned short* wbuf = (unsigned short*)(smem + 17152);    // 2 x [320][32] bf16 (2x20480 B)
  float*          xf   = (float*)(smem + 17152);             // [64 c][33 n] f32 (staging alias)
  unsigned short* vb   = (unsigned short*)smem;              // [256][40] bf16 (epilogue alias)

  const int t  = threadIdx.x;
  const int nt = blockIdx.x, b = blockIdx.y;

  // ---- stage x^T tile [32 n][256 c]: 4 rounds of 64 channels ----
  const int cs = t >> 3, nq8 = t & 7;       // cs 0..63, nq8*4 = n-quad
  for (int ct = 0; ct < 4; ++ct) {
    if (ct) __syncthreads();                // xf reuse
    float4 f = *reinterpret_cast<const float4*>(
        &x[(((size_t)((b << 8) + (ct << 6) + cs)) << 12) + (nt << 5) + (nq8 << 2)]);
    xf[cs * 33 + (nq8 << 2) + 0] = f.x;
    xf[cs * 33 + (nq8 << 2) + 1] = f.y;
    xf[cs * 33 + (nq8 << 2) + 2] = f.z;
    xf[cs * 33 + (nq8 << 2) + 3] = f.w;
    __syncthreads();
    int nl = t >> 4;            // 0..31
    int cq = (t & 15) << 2;     // 0..60
    ushort4 o;
    o.x = f2bf(xf[(cq + 0) * 33 + nl]);
    o.y = f2bf(xf[(cq + 1) * 33 + nl]);
    o.z = f2bf(xf[(cq + 2) * 33 + nl]);
    o.w = f2bf(xf[(cq + 3) * 33 + nl]);
    *reinterpret_cast<ushort4*>(&xs[nl * 268 + (ct << 6) + cq]) = o;
  }
  __syncthreads();   // xf dead from here; wbuf region free

  // Wb slice staging: 1280 16B-units: row = idx>>2 (0..319), seg = idx&3.
  // LDS[row][seg] = Wb[row][ks*32 + (seg ^ fsw(row))*8], fsw = (row^(row>>2))&3
  auto STAGEWB = [&](int ks, int buf) {
#pragma unroll
    for (int r = 0; r < 3; ++r) {
      int idx = (r << 9) + t;
      if (idx < 1280) {
        int row = idx >> 2, seg = idx & 3;
        int sseg = seg ^ ((row ^ (row >> 2)) & 3);
        const unsigned short* g = Wb + (((size_t)row) << 8) + (ks << 5) + (sseg << 3);
        __builtin_amdgcn_global_load_lds(
            (const __attribute__((address_space(1))) void*)g,
            (__attribute__((address_space(3))) void*)(wbuf + buf * 10240 + idx * 8),
            16, 0, 0);
      }
    }
  };

  STAGEWB(0, 0);
  __syncthreads();

  const int lane = t & 63, w = t >> 6, col = lane & 15, hi = lane >> 4;
  const int nw = w & 1, rh = w >> 1;       // n-half, row-quarter (80 rows)
  f32x4 zero4 = {0.f, 0.f, 0.f, 0.f};
  f32x4 acc[5];
#pragma unroll
  for (int rc = 0; rc < 5; ++rc) acc[rc] = zero4;

#pragma unroll 1
  for (int ks = 0; ks < 8; ++ks) {
    const unsigned short* wB = wbuf + (ks & 1) * 10240;
    if (ks < 7) STAGEWB(ks + 1, (ks & 1) ^ 1);
    short8v af = *reinterpret_cast<const short8v*>(
        &xs[((nw << 4) + col) * 268 + (ks << 5) + (hi << 3)]);
#pragma unroll
    for (int rc = 0; rc < 5; ++rc) {
      int row = rh * 80 + (rc << 4) + col;
      int sw = hi ^ ((row ^ (row >> 2)) & 3);
      short8v bf = *reinterpret_cast<const short8v*>(wB + row * 32 + (sw << 3));
      acc[rc] = __builtin_amdgcn_mfma_f32_16x16x32_bf16(af, bf, acc[rc], 0, 0, 0);
    }
    __syncthreads();   // drains vmcnt (next-slice gload_lds) + lgkm
  }

  // ---- Q/K outputs (rh==0: rows 0..79 -> Q 0..31, K 32..63, V 64..79) ----
  if (rh == 0) {
#pragma unroll
    for (int rc = 0; rc < 2; ++rc)
#pragma unroll
      for (int r = 0; r < 4; ++r) {
        int n = (nt << 5) + (nw << 4) + (hi << 2) + r;
        Qt[(((size_t)((b << 12) + n)) << 5) + (rc << 4) + col] = f2bf(acc[rc][r]);
      }
#pragma unroll
    for (int rc = 2; rc < 4; ++rc)
#pragma unroll
      for (int r = 0; r < 4; ++r) {
        int n = (nt << 5) + (nw << 4) + (hi << 2) + r;
        Kt[(((size_t)((b << 12) + n)) << 5) + ((rc - 2) << 4) + col] = f2bf(acc[rc][r]);
      }
  }

  // ---- V channels -> vb[ch][40] (xs/wbuf-buf0 dead; alias) ----
  {
    const int nb = (nw << 4) + (hi << 2);
    const int rcStart = (rh == 0) ? 4 : 0;
#pragma unroll
    for (int rc = 0; rc < 5; ++rc) {
      if (rc < rcStart) continue;
      int ch = rh * 80 + (rc << 4) + col - 64;
#pragma unroll
      for (int r = 0; r < 4; ++r)
        vb[ch * 40 + nb + r] = f2bf(acc[rc][r]);
    }
  }
  __syncthreads();

  // ---- coalesced V store: 1024 x 16B units (4 per channel row) ----
#pragma unroll
  for (int p = 0; p < 2; ++p) {
    int idx = (p << 9) + t;
    int c = idx >> 2, off = idx & 3;
    int offp = off ^ (c & 3);   // bank spread; same 64B global segment set
    int4 dv = *reinterpret_cast<const int4*>(&vb[c * 40 + (offp << 3)]);
    *reinterpret_cast<int4*>(
        &V[(((size_t)((b << 8) + c)) << 12) + (nt << 5) + (offp << 3)]) = dv;
  }
}

// ---------------- kernel 2: flash attention ----------------
// grid 512 = (b 4) x (ch 2) x (qt 64). 8 waves: g = KV-half, wg = col-group/ch-slice.
// K/V direct from L2 into regs, prefetch across single lgkm-only barrier per phase.
// amdgpu_waves_per_eu(4,4): LDS caps at 2 blocks/CU = 4 waves/EU anyway; pin it so the
// compiler allocates the full 128 unified regs/wave and keeps kf/vf prefetch live.
__global__ void __launch_bounds__(512)
__attribute__((amdgpu_waves_per_eu(4, 4)))
k_attn(const unsigned short* __restrict__ Qt,
       const unsigned short* __restrict__ Kt,
       const unsigned short* __restrict__ Vv,
       const float* __restrict__ x,
       float* __restrict__ out) {
  __shared__ unsigned short Qs[64][40];
  __shared__ __align__(16) unsigned short Pt[2][2][64 * 64];  // [g][parity], 16B-unit XOR swz
  __shared__ float Sc[2][2][64];
  __shared__ float Mm[2][64], Ll[2][64];
  __shared__ float Ob[4][16][64];

  const int t = threadIdx.x, bx = blockIdx.x;
  const int xcd = bx & 7;                 // XCD-locality: fixed (b,ch) per XCD
  const int b = xcd >> 1, ch = xcd & 1;
  const int qt = bx >> 3;                 // 0..63
  const int lane = t & 63, w = t >> 6, col = lane & 15, hi = lane >> 4;
  const int g = w >> 2, wg = w & 3;
  const int cBase = (ch << 7) + (wg << 5);

  if (t < 256) {  // stage Q tile [64][32]
    const int mr = t >> 2, u = t & 3;
    int4 d = *reinterpret_cast<const int4*>(
        Qt + (((size_t)((b << 12) + (qt << 6) + mr)) << 5) + (u << 3));
    *reinterpret_cast<int4*>(&Qs[mr][u << 3]) = d;
  }

  const unsigned short* KtB = Kt + (((size_t)(b << 12)) << 5);
  const unsigned short* VvB = Vv + (((size_t)((b << 8) + cBase)) << 12);

  const int kt0 = g << 5;
  int m0 = kt0 << 6;
  short8v kf[4], vf[4];
#pragma unroll
  for (int mb = 0; mb < 4; ++mb)
    kf[mb] = *reinterpret_cast<const short8v*>(
        KtB + (((size_t)(m0 + (mb << 4) + col)) << 5) + (hi << 3));
#pragma unroll
  for (int ks = 0; ks < 2; ++ks)
#pragma unroll
    for (int cb = 0; cb < 2; ++cb)
      vf[(ks << 1) + cb] = *reinterpret_cast<const short8v*>(
          VvB + (((size_t)((cb << 4) + col)) << 12) + m0 + (ks << 5) + (hi << 3));
  __syncthreads();
  const short8v qf = *reinterpret_cast<const short8v*>(&Qs[(wg << 4) + col][hi << 3]);

  f32x4 zero4 = {0.f, 0.f, 0.f, 0.f};
  f32x4 o_acc[2][4];
#pragma unroll
  for (int cb = 0; cb < 2; ++cb)
#pragma unroll
    for (int nc = 0; nc < 4; ++nc) o_acc[cb][nc] = zero4;
  float m_run = -3e38f, l_run = 0.f;

#pragma unroll 1
  for (int i = 0; i < 32; ++i) {
    const int p = i & 1;
    const int iNext = (i < 31) ? (i + 1) : 31;
    const int mN = (kt0 + iNext) << 6;

    // ---- S^T slice: rows m (4 chunks), cols n = wg*16..+15 ----
    f32x4 s_acc[4];
#pragma unroll
    for (int mb = 0; mb < 4; ++mb)
      s_acc[mb] = __builtin_amdgcn_mfma_f32_16x16x32_bf16(kf[mb], qf, zero4, 0, 0, 0);
    // K prefetch next tile (WAR on kf orders after the MFMAs)
#pragma unroll
    for (int mb = 0; mb < 4; ++mb)
      kf[mb] = *reinterpret_cast<const short8v*>(
          KtB + (((size_t)(mN + (mb << 4) + col)) << 5) + (hi << 3));

    // ---- wave-local online softmax (column n = qt*64 + wg*16 + col) ----
    float tm = -3e38f;
#pragma unroll
    for (int mb = 0; mb < 4; ++mb)
#pragma unroll
      for (int r = 0; r < 4; ++r) tm = fmaxf(tm, s_acc[mb][r]);
    tm = fmaxf(tm, __shfl_xor(tm, 16));
    tm = fmaxf(tm, __shfl_xor(tm, 32));
    // T13: skip max-update when no column in this wave grew (bit-identical: sc==1 exactly)
    float mn, sc;
    if (__any(tm > m_run)) {
      mn = fmaxf(m_run, tm);
      sc = __expf(m_run - mn);
      m_run = mn;
    } else {
      mn = m_run;
      sc = 1.f;
    }
    float ps = 0.f;
#pragma unroll
    for (int mb = 0; mb < 4; ++mb)
#pragma unroll
      for (int r = 0; r < 4; ++r) {
        float pv = __expf(s_acc[mb][r] - mn);
        s_acc[mb][r] = pv;
        ps += pv;
      }
    ps += __shfl_xor(ps, 16);
    ps += __shfl_xor(ps, 32);
    l_run = l_run * sc + ps;
    if (hi == 0) Sc[g][p][(wg << 4) + col] = sc;
    // P^T bf16 -> Pt[g][p] via v_cvt_pk_bf16_f32 (RNE, same bits as f2bf for our range)
#pragma unroll
    for (int mb = 0; mb < 4; ++mb) {
      uint2 pk2;
      asm("v_cvt_pk_bf16_f32 %0, %1, %2"
          : "=v"(pk2.x) : "v"(s_acc[mb][0]), "v"(s_acc[mb][1]));
      asm("v_cvt_pk_bf16_f32 %0, %1, %2"
          : "=v"(pk2.y) : "v"(s_acc[mb][2]), "v"(s_acc[mb][3]));
      int uu = (mb << 1) + (hi >> 1);
      int up = uu ^ (col & 7);
      *reinterpret_cast<uint2*>(
          &Pt[g][p][(((wg << 4) + col) << 6) + (up << 3) + ((hi & 1) << 2)]) = pk2;
    }

    // ---- single barrier: drain LDS writes only; V/K loads stay in flight ----
    asm volatile("s_waitcnt lgkmcnt(0)" ::: "memory");
    __builtin_amdgcn_s_barrier();

    // ---- rescale (skipped when all scl==1) + PV ----
    float scl[4];
#pragma unroll
    for (int nc = 0; nc < 4; ++nc) scl[nc] = Sc[g][p][(nc << 4) + col];
    if (__any((scl[0] != 1.f) | (scl[1] != 1.f) | (scl[2] != 1.f) | (scl[3] != 1.f))) {
#pragma unroll
      for (int cb = 0; cb < 2; ++cb)
#pragma unroll
        for (int nc = 0; nc < 4; ++nc) o_acc[cb][nc] *= scl[nc];
    }
#pragma unroll
    for (int ks = 0; ks < 2; ++ks) {
      short8v pb[4];
      int up2 = ((ks << 2) + hi) ^ (col & 7);
#pragma unroll
      for (int nc = 0; nc < 4; ++nc)
        pb[nc] = *reinterpret_cast<const short8v*>(
            &Pt[g][p][(((nc << 4) + col) << 6) + (up2 << 3)]);
#pragma unroll
      for (int cb = 0; cb < 2; ++cb)
#pragma unroll
        for (int nc = 0; nc < 4; ++nc)
          o_acc[cb][nc] = __builtin_amdgcn_mfma_f32_16x16x32_bf16(
              vf[(ks << 1) + cb], pb[nc], o_acc[cb][nc], 0, 0, 0);
    }
    // V prefetch next tile (WAR on vf orders after the MFMAs; in flight across barrier)
#pragma unroll
    for (int ks = 0; ks < 2; ++ks)
#pragma unroll
      for (int cb = 0; cb < 2; ++cb)
        vf[(ks << 1) + cb] = *reinterpret_cast<const short8v*>(
            VvB + (((size_t)((cb << 4) + col)) << 12) + mN + (ks << 5) + (hi << 3));
  }

  // ---- merge the two KV-groups + epilogue ----
  if (hi == 0) { Mm[g][(wg << 4) + col] = m_run; Ll[g][(wg << 4) + col] = l_run; }
  __syncthreads();
  float fa[4], fb[4], linv[4];
#pragma unroll
  for (int nc = 0; nc < 4; ++nc) {
    float ma = Mm[0][(nc << 4) + col], mb2 = Mm[1][(nc << 4) + col];
    float mm = fmaxf(ma, mb2);
    float ea = __expf(ma - mm), eb = __expf(mb2 - mm);
    linv[nc] = 1.f / (Ll[0][(nc << 4) + col] * ea + Ll[1][(nc << 4) + col] * eb);
    fa[nc] = ea; fb[nc] = eb;
  }
#pragma unroll
  for (int cb = 0; cb < 2; ++cb) {
    if (g == 1) {
#pragma unroll
      for (int nc = 0; nc < 4; ++nc)
#pragma unroll
        for (int r = 0; r < 4; ++r)
          Ob[wg][(nc << 2) + r][lane] = o_acc[cb][nc][r];
    }
    __syncthreads();
    if (g == 0) {
#pragma unroll
      for (int nc = 0; nc < 4; ++nc)
#pragma unroll
        for (int r = 0; r < 4; ++r) {
          float o = o_acc[cb][nc][r] * fa[nc] + Ob[wg][(nc << 2) + r][lane] * fb[nc];
          int cg = cBase + (cb << 4) + (hi << 2) + r;
          int ng = (qt << 6) + (nc << 4) + col;
          size_t off = (((size_t)((b << 8) + cg)) << 12) + ng;
          out[off] = o * linv[nc] + x[off];
        }
    }
    __syncthreads();
  }
}

// ---------------- launcher ----------------
extern "C" void kernel_launch(void* const* d_in, const int* in_sizes, int n_in,
                              void* d_out, int out_size, void* d_ws, size_t ws_size,
                              hipStream_t stream) {
  (void)in_sizes; (void)n_in; (void)out_size; (void)ws_size;
  const float* x  = (const float*)d_in[0];
  const float* Wq = (const float*)d_in[1];
  const float* Wk = (const float*)d_in[2];
  const float* Wv = (const float*)d_in[3];
  float* out = (float*)d_out;

  unsigned short* Qt = (unsigned short*)d_ws;                      // [B][N][32]  1.05 MB
  unsigned short* Kt = Qt + (size_t)Bn * Nn * CRn;                 // [B][N][32]  1.05 MB
  unsigned short* Vv = Kt + (size_t)Bn * Nn * CRn;                 // [B][C][N]   8.39 MB
  unsigned short* Wb = Vv + (size_t)Bn * Cn * Nn;                  // [320][256]  164 KB

  hipLaunchKernelGGL(k_wcast, dim3(80),        dim3(256), 0, stream, Wq, Wk, Wv, Wb);
  hipLaunchKernelGGL(k_proj,  dim3(128, 4),    dim3(512), 0, stream, Wb, x, Qt, Kt, Vv);
  hipLaunchKernelGGL(k_attn,  dim3(512),       dim3(512), 0, stream, Qt, Kt, Vv, x, out);
}